// Round 5
// baseline (992.890 us; speedup 1.0000x reference)
//
#include <hip/hip_runtime.h>
#include <math.h>

// SelfAttention B=4,S=2048,D=1024 fp32. Round 5: fine 2-phase interleave on
// the 3-buffer counted-vmcnt GEMM + full-grid tiles (BM=128, BN=256/128).
// Numerics identical to r3/r4: split-bf16 concat-K (hh+hl+lh) logit chain.
//   proj  <3,1,4>: [Q|K](8192x2048) = (Xh,Xh,Xl)x(Wch,Wcl,Wch), split store
//   VT    <1,2,4>: VT[d,tok] = Wvh . Xh^T, bf16 store
//   QKT   <3,0,4>: L = Qh.Kh + Qh.Kl + Ql.Kh, f32 store (z=2)
//   softmax in-place (P bf16 over L rows, stride 4096 u16)
//   PV    <1,0,2>: O = P . VT^T, f32 store (z=2)

typedef unsigned short u16;
typedef __attribute__((ext_vector_type(8))) short bf16x8;
typedef __attribute__((ext_vector_type(4))) float f32x4;

__device__ __forceinline__ u16 f2bf(float x) {
  unsigned u = __float_as_uint(x);
  unsigned r = (u + 0x7fffu + ((u >> 16) & 1u)) >> 16;
  return (u16)r;
}
__device__ __forceinline__ float bf2f(u16 h) {
  return __uint_as_float((unsigned)h << 16);
}

__device__ __forceinline__ void gload_lds16(const u16* g, u16* l) {
  __builtin_amdgcn_global_load_lds(
      (const __attribute__((address_space(1))) unsigned int*)(g),
      (__attribute__((address_space(3))) unsigned int*)(l), 16, 0, 0);
}

// fp32 -> hi bf16 (+ optional lo bf16), grid-stride, vectorized
template <bool LO>
__global__ __launch_bounds__(256) void split_f32_kernel(
    const float* __restrict__ in, u16* __restrict__ hi, u16* __restrict__ lo,
    long long n) {
  long long i = ((long long)blockIdx.x * 256 + threadIdx.x) * 4;
  const long long step = (long long)gridDim.x * 256 * 4;
  for (; i < n; i += step) {
    float4 x = *(const float4*)(in + i);
    float xs[4] = {x.x, x.y, x.z, x.w};
    u16 hv[4], lv[4];
#pragma unroll
    for (int j = 0; j < 4; j++) {
      hv[j] = f2bf(xs[j]);
      if (LO) lv[j] = f2bf(xs[j] - bf2f(hv[j]));
    }
    ushort4 h;
    h.x = hv[0]; h.y = hv[1]; h.z = hv[2]; h.w = hv[3];
    *(ushort4*)(hi + i) = h;
    if (LO) {
      ushort4 l;
      l.x = lv[0]; l.y = lv[1]; l.z = lv[2]; l.w = lv[3];
      *(ushort4*)(lo + i) = l;
    }
  }
}

// NT GEMM, BM=128 (M_REP=4), BN=N_REP*64. 512 thr = 8 waves (2M x 4N),
// wave tile 64 x N_REP*16. BK=32, 3 LDS slots, stage lead 2 tiles.
// LDS subtile layout per tile: elem(row,k) at u16 off
//   (row>>4)*512 + ((k>>3)&3)*128 + (row&15)*8 + (k&7)
// chunk c: row=((c>>6)<<4)+(c&15), k=((c>>4)&3)*8 (linear dest, rule #21);
// frag read rowblock rb: rb*512 + lane*8 -> conflict-free ds_read_b128.
// Per tile: phase A {read b[],a01, stage A+B0, bar, lgkm0, 8|16 MFMA, bar}
//           phase B {read a23, stage B1, bar, lgkm0, MFMA, vmcnt(LPT), bar}
// STORE: 0 = f32 Cf, 1 = split bf16 (Ch,Cl), 2 = bf16 (Ch).
template <int NSEG, int STORE, int N_REP>
__global__ __launch_bounds__(512, 4) void gemm_fine(
    const u16* __restrict__ A0, const u16* __restrict__ A1,
    const u16* __restrict__ A2, const u16* __restrict__ B0,
    const u16* __restrict__ B1, const u16* __restrict__ B2,
    float* __restrict__ Cf, u16* __restrict__ Ch, u16* __restrict__ Cl,
    int Kseg, int lda, int ldb, int ldc,
    long long sA, long long sB, long long sC) {
  constexpr int ASZ = 4096;          // 128x32 u16
  constexpr int BSZ = N_REP * 2048;  // (N_REP*64)x32 u16
  constexpr int SLOT = ASZ + BSZ;
  constexpr int LPT = 1 + N_REP / 2;  // global_load_lds per thread per tile
  __shared__ u16 lds[3 * SLOT];

  const int tid = threadIdx.x;
  const int ln = tid & 63;
  const int wid = tid >> 6;
  const int wm = wid >> 2;  // 0..1
  const int wn = wid & 3;   // 0..3
  const int m0 = blockIdx.y * 128;
  const int n0 = blockIdx.x * (N_REP * 64);
  const int z = blockIdx.z;
  const long long za = (long long)z * sA;
  const long long zb = (long long)z * sB;

  // stage source mapping (chunk -> row,k)
  const int rA = ((tid >> 6) << 4) + (tid & 15);
  const int kA = ((tid >> 4) & 3) * 8;
  const int c1 = tid + 512;
  const int rB1 = ((c1 >> 6) << 4) + (c1 & 15);
  const int kB1 = ((c1 >> 4) & 3) * 8;

  const int NT = NSEG * (Kseg >> 5);

  f32x4 acc[4][N_REP];
  const f32x4 zero = {0.f, 0.f, 0.f, 0.f};
#pragma unroll
  for (int i = 0; i < 4; i++)
#pragma unroll
    for (int j = 0; j < N_REP; j++) acc[i][j] = zero;

  auto baseA = [&](int t) -> const u16* {
    int kk = t << 5;
    const u16* p = A0;
    if (NSEG >= 2 && kk >= Kseg) { kk -= Kseg; p = A1; }
    if (NSEG >= 3 && kk >= Kseg) { kk -= Kseg; p = A2; }
    return p + za + (size_t)m0 * lda + kk;
  };
  auto baseB = [&](int t) -> const u16* {
    int kk = t << 5;
    const u16* p = B0;
    if (NSEG >= 2 && kk >= Kseg) { kk -= Kseg; p = B1; }
    if (NSEG >= 3 && kk >= Kseg) { kk -= Kseg; p = B2; }
    return p + zb + (size_t)n0 * ldb + kk;
  };
  auto stageA = [&](int t) {  // A chunk tid + B chunk tid (2 loads)
    u16* buf = lds + (t % 3) * SLOT;
    gload_lds16(baseA(t) + (size_t)rA * lda + kA, buf + tid * 8);
    gload_lds16(baseB(t) + (size_t)rA * ldb + kA, buf + ASZ + tid * 8);
  };
  auto stageB = [&](int t) {  // B chunk tid+512 (1 load, N_REP==4 only)
    if (N_REP == 4) {
      u16* buf = lds + (t % 3) * SLOT;
      gload_lds16(baseB(t) + (size_t)rB1 * ldb + kB1, buf + ASZ + c1 * 8);
    }
  };

  // prologue: tiles 0,1 fully staged; tile 0 landed (<=LPT newest in flight)
  stageA(0); stageB(0);
  stageA(1); stageB(1);
  if (LPT == 3) asm volatile("s_waitcnt vmcnt(3)" ::: "memory");
  else         asm volatile("s_waitcnt vmcnt(2)" ::: "memory");
  __builtin_amdgcn_s_barrier();
  __builtin_amdgcn_sched_barrier(0);

  for (int t = 0; t < NT; ++t) {
    const u16* Abuf = lds + (t % 3) * SLOT;
    const u16* Bbuf = Abuf + ASZ;
    const int fo = ln * 8;
    bf16x8 b[N_REP], a01[2], a23[2];
    // ---- phase A ----
#pragma unroll
    for (int j = 0; j < N_REP; ++j)
      b[j] = *(const bf16x8*)(Bbuf + (wn * N_REP + j) * 512 + fo);
    a01[0] = *(const bf16x8*)(Abuf + (wm * 4 + 0) * 512 + fo);
    a01[1] = *(const bf16x8*)(Abuf + (wm * 4 + 1) * 512 + fo);
    if (t + 2 < NT) stageA(t + 2);
    __builtin_amdgcn_s_barrier();
    asm volatile("s_waitcnt lgkmcnt(0)" ::: "memory");
    __builtin_amdgcn_sched_barrier(0);
    __builtin_amdgcn_s_setprio(1);
#pragma unroll
    for (int mi = 0; mi < 2; ++mi)
#pragma unroll
      for (int ni = 0; ni < N_REP; ++ni)
        acc[mi][ni] = __builtin_amdgcn_mfma_f32_16x16x32_bf16(
            a01[mi], b[ni], acc[mi][ni], 0, 0, 0);
    __builtin_amdgcn_s_setprio(0);
    __builtin_amdgcn_sched_barrier(0);
    __builtin_amdgcn_s_barrier();
    // ---- phase B ----
    a23[0] = *(const bf16x8*)(Abuf + (wm * 4 + 2) * 512 + fo);
    a23[1] = *(const bf16x8*)(Abuf + (wm * 4 + 3) * 512 + fo);
    if (t + 2 < NT) stageB(t + 2);
    __builtin_amdgcn_s_barrier();
    asm volatile("s_waitcnt lgkmcnt(0)" ::: "memory");
    __builtin_amdgcn_sched_barrier(0);
    __builtin_amdgcn_s_setprio(1);
#pragma unroll
    for (int mi = 0; mi < 2; ++mi)
#pragma unroll
      for (int ni = 0; ni < N_REP; ++ni)
        acc[2 + mi][ni] = __builtin_amdgcn_mfma_f32_16x16x32_bf16(
            a23[mi], b[ni], acc[2 + mi][ni], 0, 0, 0);
    __builtin_amdgcn_s_setprio(0);
    __builtin_amdgcn_sched_barrier(0);
    // ---- end of tile: counted drain (never 0 while staging continues) ----
    if (t + 1 < NT) {
      if (t + 2 < NT) {
        if (LPT == 3) asm volatile("s_waitcnt vmcnt(3)" ::: "memory");
        else         asm volatile("s_waitcnt vmcnt(2)" ::: "memory");
      } else {
        asm volatile("s_waitcnt vmcnt(0)" ::: "memory");
      }
      __builtin_amdgcn_s_barrier();
      __builtin_amdgcn_sched_barrier(0);
    }
  }

  // epilogue: C/D layout col=lane&15, row=(lane>>4)*4+reg (validated r2-r4)
  const int orow = (ln >> 4) * 4;
  const int ocol = ln & 15;
#pragma unroll
  for (int mi = 0; mi < 4; ++mi)
#pragma unroll
    for (int ni = 0; ni < N_REP; ++ni) {
      const int rbase = m0 + wm * 64 + mi * 16 + orow;
      const int cc = n0 + wn * (N_REP * 16) + ni * 16 + ocol;
#pragma unroll
      for (int i = 0; i < 4; ++i) {
        const float v = acc[mi][ni][i];
        const long long off =
            (long long)(rbase + i) * ldc + cc + (long long)z * sC;
        if (STORE == 0) {
          Cf[off] = v;
        } else if (STORE == 1) {
          const u16 h = f2bf(v);
          Ch[off] = h;
          Cl[off] = f2bf(v - bf2f(h));
        } else {
          Ch[off] = f2bf(v);
        }
      }
    }
}

// row softmax in place: 2048 f32 -> 2048 bf16 over same storage (row stride
// stays 4096 u16). One block per row.
__global__ __launch_bounds__(256) void softmax_inplace(float* __restrict__ L) {
  float* p = L + (size_t)blockIdx.x * 2048;
  const int t = threadIdx.x;
  const int wv = t >> 6, lnn = t & 63;

  float4 x0 = *(const float4*)(p + t * 4);
  float4 x1 = *(const float4*)(p + 1024 + t * 4);

  float m = fmaxf(fmaxf(fmaxf(x0.x, x0.y), fmaxf(x0.z, x0.w)),
                  fmaxf(fmaxf(x1.x, x1.y), fmaxf(x1.z, x1.w)));
#pragma unroll
  for (int off = 32; off; off >>= 1) m = fmaxf(m, __shfl_xor(m, off));
  __shared__ float redm[4];
  __shared__ float reds[4];
  if (lnn == 0) redm[wv] = m;
  __syncthreads();
  m = fmaxf(fmaxf(redm[0], redm[1]), fmaxf(redm[2], redm[3]));

  float e[8];
  e[0] = __expf(x0.x - m); e[1] = __expf(x0.y - m);
  e[2] = __expf(x0.z - m); e[3] = __expf(x0.w - m);
  e[4] = __expf(x1.x - m); e[5] = __expf(x1.y - m);
  e[6] = __expf(x1.z - m); e[7] = __expf(x1.w - m);
  float s = e[0] + e[1] + e[2] + e[3] + e[4] + e[5] + e[6] + e[7];
#pragma unroll
  for (int off = 32; off; off >>= 1) s += __shfl_xor(s, off);
  if (lnn == 0) reds[wv] = s;
  __syncthreads();
  const float inv = 1.f / (reds[0] + reds[1] + reds[2] + reds[3]);

  u16* q = (u16*)p;
  ushort4 o0, o1;
  o0.x = f2bf(e[0] * inv); o0.y = f2bf(e[1] * inv);
  o0.z = f2bf(e[2] * inv); o0.w = f2bf(e[3] * inv);
  o1.x = f2bf(e[4] * inv); o1.y = f2bf(e[5] * inv);
  o1.z = f2bf(e[6] * inv); o1.w = f2bf(e[7] * inv);
  *(ushort4*)(q + t * 4) = o0;
  *(ushort4*)(q + 1024 + t * 4) = o1;
}

extern "C" void kernel_launch(void* const* d_in, const int* in_sizes, int n_in,
                              void* d_out, int out_size, void* d_ws, size_t ws_size,
                              hipStream_t stream) {
  constexpr int Bn = 4, S = 2048, D = 1024;
  constexpr long long TOK = (long long)Bn * S;  // 8192
  constexpr long long DD = (long long)D * D;
  const float* X = (const float*)d_in[0];
  const float* Wq = (const float*)d_in[1];
  const float* Wk = (const float*)d_in[2];
  const float* Wv = (const float*)d_in[3];
  float* out = (float*)d_out;
  const dim3 blk(256);
  const dim3 gblk(512);

  char* w = (char*)d_ws;
  auto au16 = [&](long long n) { u16* p = (u16*)w; w += n * 2; return p; };

  const bool mid = ws_size >= (size_t)140 * 1000 * 1000;

  if (mid) {
    u16* Xh = au16(TOK * D);
    u16* Xl = au16(TOK * D);
    u16* Wch = au16(2 * DD);  // [Wq;Wk] hi
    u16* Wcl = au16(2 * DD);
    u16* Wvh = au16(DD);
    u16* QKh = au16(TOK * 2 * D);  // cols 0..1023 = Q, 1024..2047 = K
    u16* QKl = au16(TOK * 2 * D);
    u16* VT = au16((long long)D * TOK);  // [D][8192], col = b*2048+s
    float* Lf = (float*)d_ws;  // aliases [Xh|Xl] exactly (2*S*S*4 bytes), G=2
    const int G = 2;

    split_f32_kernel<true><<<2048, blk, 0, stream>>>(X, Xh, Xl, TOK * D);
    split_f32_kernel<true><<<512, blk, 0, stream>>>(Wq, Wch, Wcl, DD);
    split_f32_kernel<true><<<512, blk, 0, stream>>>(Wk, Wch + DD, Wcl + DD, DD);
    split_f32_kernel<false><<<512, blk, 0, stream>>>(Wv, Wvh, nullptr, DD);

    // fused Q|K projection: M=8192, N=2048 -> grid (8,64) = 512 blocks
    gemm_fine<3, 1, 4><<<dim3(8, 64, 1), gblk, 0, stream>>>(
        Xh, Xh, Xl, Wch, Wcl, Wch, nullptr, QKh, QKl,
        D, D, D, 2 * D, 0, 0, 0);
    // VT[d,tok] = Wvh . Xh^T : M=1024, N=8192 -> grid (32,8) = 256
    gemm_fine<1, 2, 4><<<dim3(32, 8, 1), gblk, 0, stream>>>(
        Wvh, nullptr, nullptr, Xh, nullptr, nullptr, nullptr, VT, nullptr,
        D, D, D, (int)TOK, 0, 0, 0);

    for (int g = 0; g < Bn / G; ++g) {
      const long long ro = (long long)g * G * S * 2 * D;  // u16 row offset
      // L[z] = Qh.Kh + Qh.Kl + Ql.Kh : M=N=2048, z=2 -> (8,16,2) = 256
      gemm_fine<3, 0, 4><<<dim3(8, 16, G), gblk, 0, stream>>>(
          QKh + ro, QKh + ro, QKl + ro,
          QKh + ro + D, QKl + ro + D, QKh + ro + D,
          Lf, nullptr, nullptr, D, 2 * D, 2 * D, S,
          (long long)S * 2 * D, (long long)S * 2 * D, (long long)S * S);
      softmax_inplace<<<dim3(G * S), blk, 0, stream>>>(Lf);
      // O[z] = P . VT^T : M=2048, N=1024, z=2 -> (8,16,2) = 256 (N_REP=2)
      gemm_fine<1, 0, 2><<<dim3(8, 16, G), gblk, 0, stream>>>(
          (const u16*)Lf, nullptr, nullptr, VT + (long long)g * G * S,
          nullptr, nullptr, out + (long long)g * G * S * D, nullptr, nullptr,
          S, 2 * S, (int)TOK, D,
          (long long)S * S * 2, (long long)S, (long long)S * D);
    }
  } else {
    // Low tier (~93 MB): per-batch (not expected to run; ws >= 140MB observed)
    u16* Xh = au16(TOK * D);
    u16* Xl = au16(TOK * D);
    u16* Wch = au16(2 * DD);
    u16* Wcl = au16(2 * DD);
    u16* Wvh = au16(DD);
    u16* QKhb = au16((long long)S * 2 * D);
    u16* QKlb = au16((long long)S * 2 * D);
    u16* VTb = au16((long long)D * S);
    float* Lb = (float*)w;

    split_f32_kernel<true><<<2048, blk, 0, stream>>>(X, Xh, Xl, TOK * D);
    split_f32_kernel<true><<<512, blk, 0, stream>>>(Wq, Wch, Wcl, DD);
    split_f32_kernel<true><<<512, blk, 0, stream>>>(Wk, Wch + DD, Wcl + DD, DD);
    split_f32_kernel<false><<<512, blk, 0, stream>>>(Wv, Wvh, nullptr, DD);

    for (int b = 0; b < Bn; ++b) {
      const long long xo = (long long)b * S * D;
      gemm_fine<3, 1, 4><<<dim3(8, 16, 1), gblk, 0, stream>>>(
          Xh + xo, Xh + xo, Xl + xo, Wch, Wcl, Wch, nullptr, QKhb, QKlb,
          D, D, D, 2 * D, 0, 0, 0);
      gemm_fine<1, 2, 4><<<dim3(8, 8, 1), gblk, 0, stream>>>(
          Wvh, nullptr, nullptr, Xh + xo, nullptr, nullptr, nullptr, VTb,
          nullptr, D, D, D, S, 0, 0, 0);
      gemm_fine<3, 0, 4><<<dim3(8, 16, 1), gblk, 0, stream>>>(
          QKhb, QKhb, QKlb, QKhb + D, QKlb + D, QKhb + D,
          Lb, nullptr, nullptr, D, 2 * D, 2 * D, S, 0, 0, 0);
      softmax_inplace<<<dim3(S), blk, 0, stream>>>(Lb);
      gemm_fine<1, 0, 2><<<dim3(8, 16, 1), gblk, 0, stream>>>(
          (const u16*)Lb, nullptr, nullptr, VTb, nullptr, nullptr,
          out + xo, nullptr, nullptr, S, 2 * S, S, D, 0, 0, 0);
    }
  }
}

// Round 7
// 576.731 us; speedup vs baseline: 1.7216x; 1.7216x over previous
//
#include <hip/hip_runtime.h>
#include <math.h>

// SelfAttention B=4,S=2048,D=1024 fp32. Round 7 (r6 + compile fix):
// phase-interleaved GEMM, 4 LDS slots, stage lead 3 K-tiles, counted vmcnt
// once per tile, 16 MFMA per phase (M_REP=8). Numerics = split-bf16 concat-K.

typedef unsigned short u16;
typedef __attribute__((ext_vector_type(8))) short bf16x8;
typedef __attribute__((ext_vector_type(4))) float f32x4;

__device__ __forceinline__ u16 f2bf(float x) {
  unsigned u = __float_as_uint(x);
  unsigned r = (u + 0x7fffu + ((u >> 16) & 1u)) >> 16;
  return (u16)r;
}
__device__ __forceinline__ float bf2f(u16 h) {
  return __uint_as_float((unsigned)h << 16);
}

__device__ __forceinline__ void gload_lds16(const u16* g, u16* l) {
  __builtin_amdgcn_global_load_lds(
      (const __attribute__((address_space(1))) unsigned int*)(g),
      (__attribute__((address_space(3))) unsigned int*)(l), 16, 0, 0);
}

template <int N>
__device__ __forceinline__ void wait_vmcnt() {
  if constexpr (N == 0) asm volatile("s_waitcnt vmcnt(0)" ::: "memory");
  else if constexpr (N == 2) asm volatile("s_waitcnt vmcnt(2)" ::: "memory");
  else if constexpr (N == 3) asm volatile("s_waitcnt vmcnt(3)" ::: "memory");
  else if constexpr (N == 4) asm volatile("s_waitcnt vmcnt(4)" ::: "memory");
  else if constexpr (N == 6) asm volatile("s_waitcnt vmcnt(6)" ::: "memory");
  else if constexpr (N == 8) asm volatile("s_waitcnt vmcnt(8)" ::: "memory");
}

// fp32 -> hi bf16 (+ optional lo bf16), grid-stride, vectorized
template <bool LO>
__global__ __launch_bounds__(256) void split_f32_kernel(
    const float* __restrict__ in, u16* __restrict__ hi, u16* __restrict__ lo,
    long long n) {
  long long i = ((long long)blockIdx.x * 256 + threadIdx.x) * 4;
  const long long step = (long long)gridDim.x * 256 * 4;
  for (; i < n; i += step) {
    float4 x = *(const float4*)(in + i);
    float xs[4] = {x.x, x.y, x.z, x.w};
    u16 hv[4], lv[4];
#pragma unroll
    for (int j = 0; j < 4; j++) {
      hv[j] = f2bf(xs[j]);
      if (LO) lv[j] = f2bf(xs[j] - bf2f(hv[j]));
    }
    ushort4 h;
    h.x = hv[0]; h.y = hv[1]; h.z = hv[2]; h.w = hv[3];
    *(ushort4*)(hi + i) = h;
    if (LO) {
      ushort4 l;
      l.x = lv[0]; l.y = lv[1]; l.z = lv[2]; l.w = lv[3];
      *(ushort4*)(lo + i) = l;
    }
  }
}

// NT GEMM over NSEG K-segments. BM=32*M_REP, BN=64*N_REP, BK=32.
// 512 thr = 8 waves (2M x 4N); wave tile (M_REP*16) x (N_REP*16).
// LDS: 4 slots x (A BM*32 + B BN*32) u16; subtile layout per tile:
//   elem(row,k) at u16 off (row>>4)*512 + ((k>>3)&3)*128 + (row&15)*8 + (k&7)
//   chunk c -> row=((c>>6)<<4)+(c&15), k=((c>>4)&3)*8 (linear dest, rule #21)
//   frag read rowblock rb: rb*512 + lane*8 -> conflict-free ds_read_b128.
// Pipeline: compute tile t from slot[t&3]; stage tile t+3 into slot[(t+3)&3]
// (freed at end of tile t-1); per-tile counted vmcnt(2L) -> t+1 landed.
// Per tile: 2 phases x {ds_read, stage part, s_barrier, lgkmcnt(0),
// setprio(1) (M_REP/2)*N_REP MFMA setprio(0), [s_barrier]}.
// STORE: 0 = f32 Cf, 1 = split bf16 (Ch,Cl), 2 = bf16 (Ch).
template <int NSEG, int STORE, int M_REP, int N_REP>
__global__ __launch_bounds__(512, 2) void gemm_p(
    const u16* __restrict__ A0, const u16* __restrict__ A1,
    const u16* __restrict__ A2, const u16* __restrict__ B0,
    const u16* __restrict__ B1, const u16* __restrict__ B2,
    float* __restrict__ Cf, u16* __restrict__ Ch, u16* __restrict__ Cl,
    int Kseg, int lda, int ldb, int ldc,
    long long sA, long long sB, long long sC) {
  constexpr int BM = 32 * M_REP;
  constexpr int BN = 64 * N_REP;
  constexpr int ASZ = BM * 32;        // u16
  constexpr int BSZ = BN * 32;        // u16
  constexpr int SLOT = ASZ + BSZ;
  constexpr int LA = M_REP / 4;       // A gloads / thread / tile
  constexpr int LB = N_REP / 2;       // B gloads / thread / tile
  constexpr int L = LA + LB;
  constexpr int MH = M_REP / 2;
  __shared__ u16 lds[4 * SLOT];

  const int tid = threadIdx.x;
  const int ln = tid & 63;
  const int wid = tid >> 6;
  const int wm = wid >> 2;  // 0..1
  const int wn = wid & 3;   // 0..3
  const int m0 = blockIdx.y * BM;
  const int n0 = blockIdx.x * BN;
  const int z = blockIdx.z;
  const long long za = (long long)z * sA;
  const long long zb = (long long)z * sB;

  const int NT = NSEG * (Kseg >> 5);

  f32x4 acc[M_REP][N_REP];
  const f32x4 zero = {0.f, 0.f, 0.f, 0.f};
#pragma unroll
  for (int i = 0; i < M_REP; i++)
#pragma unroll
    for (int j = 0; j < N_REP; j++) acc[i][j] = zero;

  auto baseA = [&](int t) -> const u16* {
    int kk = t << 5;
    const u16* p = A0;
    if (NSEG >= 2 && kk >= Kseg) { kk -= Kseg; p = A1; }
    if (NSEG >= 3 && kk >= Kseg) { kk -= Kseg; p = A2; }
    return p + za + (size_t)m0 * lda + kk;
  };
  auto baseB = [&](int t) -> const u16* {
    int kk = t << 5;
    const u16* p = B0;
    if (NSEG >= 2 && kk >= Kseg) { kk -= Kseg; p = B1; }
    if (NSEG >= 3 && kk >= Kseg) { kk -= Kseg; p = B2; }
    return p + zb + (size_t)n0 * ldb + kk;
  };
  auto stageA = [&](int t) {
    u16* slot = lds + (t & 3) * SLOT;
    const u16* Ab = baseA(t);
#pragma unroll
    for (int l = 0; l < LA; ++l) {
      const int c = tid + l * 512;
      const int row = ((c >> 6) << 4) + (c & 15);
      const int kk = ((c >> 4) & 3) * 8;
      gload_lds16(Ab + (size_t)row * lda + kk, slot + c * 8);
    }
  };
  auto stageB = [&](int t) {
    u16* slot = lds + (t & 3) * SLOT + ASZ;
    const u16* Bb = baseB(t);
#pragma unroll
    for (int l = 0; l < LB; ++l) {
      const int c = tid + l * 512;
      const int row = ((c >> 6) << 4) + (c & 15);
      const int kk = ((c >> 4) & 3) * 8;
      gload_lds16(Bb + (size_t)row * ldb + kk, slot + c * 8);
    }
  };

  // prologue: tiles 0,1,2 staged (3L loads); wait until only t1,t2 (2L) fly.
  stageA(0); stageB(0);
  stageA(1); stageB(1);
  stageA(2); stageB(2);
  wait_vmcnt<2 * L>();
  __builtin_amdgcn_s_barrier();
  __builtin_amdgcn_sched_barrier(0);

  for (int t = 0; t < NT; ++t) {
    const u16* Abuf = lds + (t & 3) * SLOT;
    const u16* Bbuf = Abuf + ASZ;
    const int fo = ln * 8;
    bf16x8 b[N_REP], alo[MH], ahi[MH];
    // ---- phase 0: b[] + a-lo reads, stage A(t+3), 16 MFMA (mh=0) ----
#pragma unroll
    for (int j = 0; j < N_REP; ++j)
      b[j] = *(const bf16x8*)(Bbuf + (wn * N_REP + j) * 512 + fo);
#pragma unroll
    for (int i = 0; i < MH; ++i)
      alo[i] = *(const bf16x8*)(Abuf + (wm * M_REP + i) * 512 + fo);
    if (t + 3 < NT) stageA(t + 3);
    __builtin_amdgcn_s_barrier();
    asm volatile("s_waitcnt lgkmcnt(0)" ::: "memory");
    __builtin_amdgcn_sched_barrier(0);
    __builtin_amdgcn_s_setprio(1);
#pragma unroll
    for (int mi = 0; mi < MH; ++mi)
#pragma unroll
      for (int ni = 0; ni < N_REP; ++ni)
        acc[mi][ni] = __builtin_amdgcn_mfma_f32_16x16x32_bf16(
            alo[mi], b[ni], acc[mi][ni], 0, 0, 0);
    __builtin_amdgcn_s_setprio(0);
    __builtin_amdgcn_sched_barrier(0);
    __builtin_amdgcn_s_barrier();
    // ---- phase 1: a-hi reads, stage B(t+3), 16 MFMA (mh=1) ----
#pragma unroll
    for (int i = 0; i < MH; ++i)
      ahi[i] = *(const bf16x8*)(Abuf + (wm * M_REP + MH + i) * 512 + fo);
    if (t + 3 < NT) stageB(t + 3);
    __builtin_amdgcn_s_barrier();
    asm volatile("s_waitcnt lgkmcnt(0)" ::: "memory");
    __builtin_amdgcn_sched_barrier(0);
    __builtin_amdgcn_s_setprio(1);
#pragma unroll
    for (int mi = 0; mi < MH; ++mi)
#pragma unroll
      for (int ni = 0; ni < N_REP; ++ni)
        acc[MH + mi][ni] = __builtin_amdgcn_mfma_f32_16x16x32_bf16(
            ahi[mi], b[ni], acc[MH + mi][ni], 0, 0, 0);
    __builtin_amdgcn_s_setprio(0);
    __builtin_amdgcn_sched_barrier(0);
    // ---- tile end: counted drain (t+1 landed; t+2,t+3 may fly) ----
    if (t + 1 < NT) {
      if (t + 3 < NT)      wait_vmcnt<2 * L>();
      else if (t + 2 < NT) wait_vmcnt<L>();
      else                 wait_vmcnt<0>();
      __builtin_amdgcn_s_barrier();
      __builtin_amdgcn_sched_barrier(0);
    }
  }

  // epilogue: C/D layout col=lane&15, row=(lane>>4)*4+reg (validated r2-r5)
  const int orow = (ln >> 4) * 4;
  const int ocol = ln & 15;
#pragma unroll
  for (int mi = 0; mi < M_REP; ++mi)
#pragma unroll
    for (int ni = 0; ni < N_REP; ++ni) {
      const int rbase = m0 + wm * (M_REP * 16) + mi * 16 + orow;
      const int cc = n0 + wn * (N_REP * 16) + ni * 16 + ocol;
#pragma unroll
      for (int i = 0; i < 4; ++i) {
        const float v = acc[mi][ni][i];
        const long long off =
            (long long)(rbase + i) * ldc + cc + (long long)z * sC;
        if (STORE == 0) {
          Cf[off] = v;
        } else if (STORE == 1) {
          const u16 h = f2bf(v);
          Ch[off] = h;
          Cl[off] = f2bf(v - bf2f(h));
        } else {
          Ch[off] = f2bf(v);
        }
      }
    }
}

// row softmax in place: 2048 f32 -> 2048 bf16 over same storage (row stride
// stays 4096 u16). One block per row.
__global__ __launch_bounds__(256) void softmax_inplace(float* __restrict__ L) {
  float* p = L + (size_t)blockIdx.x * 2048;
  const int t = threadIdx.x;
  const int wv = t >> 6, lnn = t & 63;

  float4 x0 = *(const float4*)(p + t * 4);
  float4 x1 = *(const float4*)(p + 1024 + t * 4);

  float m = fmaxf(fmaxf(fmaxf(x0.x, x0.y), fmaxf(x0.z, x0.w)),
                  fmaxf(fmaxf(x1.x, x1.y), fmaxf(x1.z, x1.w)));
#pragma unroll
  for (int off = 32; off; off >>= 1) m = fmaxf(m, __shfl_xor(m, off));
  __shared__ float redm[4];
  __shared__ float reds[4];
  if (lnn == 0) redm[wv] = m;
  __syncthreads();
  m = fmaxf(fmaxf(redm[0], redm[1]), fmaxf(redm[2], redm[3]));

  float e[8];
  e[0] = __expf(x0.x - m); e[1] = __expf(x0.y - m);
  e[2] = __expf(x0.z - m); e[3] = __expf(x0.w - m);
  e[4] = __expf(x1.x - m); e[5] = __expf(x1.y - m);
  e[6] = __expf(x1.z - m); e[7] = __expf(x1.w - m);
  float s = e[0] + e[1] + e[2] + e[3] + e[4] + e[5] + e[6] + e[7];
#pragma unroll
  for (int off = 32; off; off >>= 1) s += __shfl_xor(s, off);
  if (lnn == 0) reds[wv] = s;
  __syncthreads();
  const float inv = 1.f / (reds[0] + reds[1] + reds[2] + reds[3]);

  u16* q = (u16*)p;
  ushort4 o0, o1;
  o0.x = f2bf(e[0] * inv); o0.y = f2bf(e[1] * inv);
  o0.z = f2bf(e[2] * inv); o0.w = f2bf(e[3] * inv);
  o1.x = f2bf(e[4] * inv); o1.y = f2bf(e[5] * inv);
  o1.z = f2bf(e[6] * inv); o1.w = f2bf(e[7] * inv);
  *(ushort4*)(q + t * 4) = o0;
  *(ushort4*)(q + 1024 + t * 4) = o1;
}

extern "C" void kernel_launch(void* const* d_in, const int* in_sizes, int n_in,
                              void* d_out, int out_size, void* d_ws, size_t ws_size,
                              hipStream_t stream) {
  constexpr int Bn = 4, S = 2048, D = 1024;
  constexpr long long TOK = (long long)Bn * S;  // 8192
  constexpr long long DD = (long long)D * D;
  const float* X = (const float*)d_in[0];
  const float* Wq = (const float*)d_in[1];
  const float* Wk = (const float*)d_in[2];
  const float* Wv = (const float*)d_in[3];
  float* out = (float*)d_out;
  const dim3 blk(256);
  const dim3 gblk(512);

  char* w = (char*)d_ws;
  auto au16 = [&](long long n) { u16* p = (u16*)w; w += n * 2; return p; };

  const bool full = ws_size >= (size_t)195100000ULL;
  const bool mid = ws_size >= (size_t)128500000ULL;

  if (full || mid) {
    u16* Xh = au16(TOK * D);
    u16* Xl = au16(TOK * D);
    u16* Wch = au16(2 * DD);  // [Wq;Wk] hi
    u16* Wcl = au16(2 * DD);
    u16* Wvh = au16(DD);
    u16* QKh = au16(TOK * 2 * D);  // cols 0..1023 = Q, 1024..2047 = K
    u16* QKl = au16(TOK * 2 * D);
    u16* VT = au16((long long)D * TOK);  // [1024][8192], col = b*2048+s
    float* Lf;
    int G;
    if (full) {
      Lf = (float*)w;  // 4*S*S f32
      G = 4;
    } else {
      Lf = (float*)d_ws;  // aliases [Xh|Xl] exactly (2*S*S*4 = 33.55 MB)
      G = 2;
    }

    split_f32_kernel<true><<<2048, blk, 0, stream>>>(X, Xh, Xl, TOK * D);
    split_f32_kernel<true><<<512, blk, 0, stream>>>(Wq, Wch, Wcl, DD);
    split_f32_kernel<true><<<512, blk, 0, stream>>>(Wk, Wch + DD, Wcl + DD, DD);
    split_f32_kernel<false><<<512, blk, 0, stream>>>(Wv, Wvh, nullptr, DD);

    // fused Q|K projection: M=8192, N=2048 -> (8,32) = 256 blocks
    gemm_p<3, 1, 8, 4><<<dim3(8, 32, 1), gblk, 0, stream>>>(
        Xh, Xh, Xl, Wch, Wcl, Wch, nullptr, QKh, QKl,
        D, D, D, 2 * D, 0, 0, 0);
    // VT[e,tok] = Wvh . Xh^T : M=1024, N=8192, (8,2) -> (64,4) = 256 blocks
    gemm_p<1, 2, 8, 2><<<dim3(64, 4, 1), gblk, 0, stream>>>(
        Wvh, nullptr, nullptr, Xh, nullptr, nullptr, nullptr, VT, nullptr,
        D, D, D, (int)TOK, 0, 0, 0);

    for (int g = 0; g < Bn / G; ++g) {
      const long long ro = (long long)g * G * S * 2 * D;  // u16 row offset
      if (G == 4) {
        // L[z] = Qh.Kh + Qh.Kl + Ql.Kh : (8,8,4) = 256 blocks
        gemm_p<3, 0, 8, 4><<<dim3(8, 8, 4), gblk, 0, stream>>>(
            QKh, QKh, QKl, QKh + D, QKl + D, QKh + D,
            Lf, nullptr, nullptr, D, 2 * D, 2 * D, S,
            (long long)S * 2 * D, (long long)S * 2 * D, (long long)S * S);
      } else {
        // (4,4) variant: (8,16,2) = 256 blocks
        gemm_p<3, 0, 4, 4><<<dim3(8, 16, 2), gblk, 0, stream>>>(
            QKh + ro, QKh + ro, QKl + ro,
            QKh + ro + D, QKl + ro + D, QKh + ro + D,
            Lf, nullptr, nullptr, D, 2 * D, 2 * D, S,
            (long long)S * 2 * D, (long long)S * 2 * D, (long long)S * S);
      }
      softmax_inplace<<<dim3(G * S), blk, 0, stream>>>(Lf);
      if (G == 4) {
        // O[z] = P . VT^T : (8,8,4) = 256 blocks (8,2 variant)
        gemm_p<1, 0, 8, 2><<<dim3(8, 8, 4), gblk, 0, stream>>>(
            (const u16*)Lf, nullptr, nullptr, VT, nullptr, nullptr,
            out, nullptr, nullptr, S, 2 * S, (int)TOK, D,
            (long long)S * S * 2, (long long)S, (long long)S * D);
      } else {
        // (4,2) variant: (8,16,2) = 256 blocks
        gemm_p<1, 0, 4, 2><<<dim3(8, 16, 2), gblk, 0, stream>>>(
            (const u16*)Lf, nullptr, nullptr, VT + (long long)g * G * S,
            nullptr, nullptr, out + (long long)g * G * S * D, nullptr,
            nullptr, S, 2 * S, (int)TOK, D,
            (long long)S * S * 2, (long long)S, (long long)S * D);
      }
    }
  } else {
    // Low tier (~82 MB): per-batch fallback (correctness-first)
    u16* Xh = au16(TOK * D);
    u16* Xl = au16(TOK * D);
    u16* Wch = au16(2 * DD);
    u16* Wcl = au16(2 * DD);
    u16* Wvh = au16(DD);
    u16* QKhb = au16((long long)S * 2 * D);
    u16* QKlb = au16((long long)S * 2 * D);
    u16* VTb = au16((long long)D * S);
    float* Lb = (float*)w;

    split_f32_kernel<true><<<2048, blk, 0, stream>>>(X, Xh, Xl, TOK * D);
    split_f32_kernel<true><<<512, blk, 0, stream>>>(Wq, Wch, Wcl, DD);
    split_f32_kernel<true><<<512, blk, 0, stream>>>(Wk, Wch + DD, Wcl + DD, DD);
    split_f32_kernel<false><<<512, blk, 0, stream>>>(Wv, Wvh, nullptr, DD);

    for (int b = 0; b < Bn; ++b) {
      const long long xo = (long long)b * S * D;
      gemm_p<3, 1, 8, 4><<<dim3(8, 8, 1), gblk, 0, stream>>>(
          Xh + xo, Xh + xo, Xl + xo, Wch, Wcl, Wch, nullptr, QKhb, QKlb,
          D, D, D, 2 * D, 0, 0, 0);
      gemm_p<1, 2, 8, 2><<<dim3(16, 4, 1), gblk, 0, stream>>>(
          Wvh, nullptr, nullptr, Xh + xo, nullptr, nullptr, nullptr, VTb,
          nullptr, D, D, D, S, 0, 0, 0);
      gemm_p<3, 0, 4, 4><<<dim3(8, 16, 1), gblk, 0, stream>>>(
          QKhb, QKhb, QKlb, QKhb + D, QKlb + D, QKhb + D,
          Lb, nullptr, nullptr, D, 2 * D, 2 * D, S, 0, 0, 0);
      softmax_inplace<<<dim3(S), blk, 0, stream>>>(Lb);
      gemm_p<1, 0, 4, 2><<<dim3(8, 16, 1), gblk, 0, stream>>>(
          (const u16*)Lb, nullptr, nullptr, VTb, nullptr, nullptr,
          out + xo, nullptr, nullptr, S, 2 * S, S, D, 0, 0, 0);
    }
  }
}

// Round 8
// 559.952 us; speedup vs baseline: 1.7732x; 1.0300x over previous
//
#include <hip/hip_runtime.h>
#include <math.h>

// SelfAttention B=4,S=2048,D=1024 fp32. Round 8: faithful m201 8-phase port.
// GEMM: 256^2 tile, BK=64, 8 waves, 2 LDS buffers (128KB), 4 phases/K-tile,
// one half-tile staged per phase, vmcnt(4) at phases 2,4 only (never 0).
// Numerics: split-bf16 concat-K (hh+hl+lh) logit chain, validated r2-r7.

typedef unsigned short u16;
typedef __attribute__((ext_vector_type(8))) short bf16x8;
typedef __attribute__((ext_vector_type(4))) float f32x4;

__device__ __forceinline__ u16 f2bf(float x) {
  unsigned u = __float_as_uint(x);
  unsigned r = (u + 0x7fffu + ((u >> 16) & 1u)) >> 16;
  return (u16)r;
}
__device__ __forceinline__ float bf2f(u16 h) {
  return __uint_as_float((unsigned)h << 16);
}

__device__ __forceinline__ void gload_lds16(const u16* g, u16* l) {
  __builtin_amdgcn_global_load_lds(
      (const __attribute__((address_space(1))) unsigned int*)(g),
      (__attribute__((address_space(3))) unsigned int*)(l), 16, 0, 0);
}

template <int N>
__device__ __forceinline__ void wait_vmcnt() {
  if constexpr (N == 0) asm volatile("s_waitcnt vmcnt(0)" ::: "memory");
  else if constexpr (N == 4) asm volatile("s_waitcnt vmcnt(4)" ::: "memory");
}

// fp32 -> hi bf16 (+ optional lo bf16), grid-stride, vectorized
template <bool LO>
__global__ __launch_bounds__(256) void split_f32_kernel(
    const float* __restrict__ in, u16* __restrict__ hi, u16* __restrict__ lo,
    long long n) {
  long long i = ((long long)blockIdx.x * 256 + threadIdx.x) * 4;
  const long long step = (long long)gridDim.x * 256 * 4;
  for (; i < n; i += step) {
    float4 x = *(const float4*)(in + i);
    float xs[4] = {x.x, x.y, x.z, x.w};
    u16 hv[4], lv[4];
#pragma unroll
    for (int j = 0; j < 4; j++) {
      hv[j] = f2bf(xs[j]);
      if (LO) lv[j] = f2bf(xs[j] - bf2f(hv[j]));
    }
    ushort4 h;
    h.x = hv[0]; h.y = hv[1]; h.z = hv[2]; h.w = hv[3];
    *(ushort4*)(hi + i) = h;
    if (LO) {
      ushort4 l;
      l.x = lv[0]; l.y = lv[1]; l.z = lv[2]; l.w = lv[3];
      *(ushort4*)(lo + i) = l;
    }
  }
}

// NT GEMM over NSEG K-segments. BM=BN=256, BK=64. 512 thr = 8 waves (2Mx4N),
// per-wave 128x64 C (acc[8][4]). LDS: 2 buffers x [A-k0|A-k1|B-k0|B-k1]
// sub-tiles; each sub-tile 256x32 u16 in the validated layout:
//   elem(row,k) at u16 off (row>>4)*512 + ((k>>3)&3)*128 + (row&15)*8 + (k&7)
//   stage chunk c -> row=((c>>6)<<4)+(c&15), k=((c>>4)&3)*8 (linear dest)
//   frag read rowblock rb: rb*512 + lane*8 -> conflict-free ds_read_b128.
// Schedule per K-tile t (4 phases, quadrant = (k-half, m-half)):
//   ph1 (k0,m0): read b0[4]+a[4], stage A-k0(t+1), bar, lgkm0, 16 MFMA, bar
//   ph2 (k0,m1): read a[4],       stage B-k0(t+1), bar, lgkm0, 16 MFMA,
//                vmcnt(4), bar
//   ph3 (k1,m0): read b1[4]+a[4], stage A-k1(t+1), bar, lgkm0, 16 MFMA, bar
//   ph4 (k1,m1): read a[4],       stage B-k1(t+1), bar, lgkm0, 16 MFMA,
//                vmcnt(4), bar
// Ledger: ph3 needs A/B-k1(t) [staged t-1 ph3/4; 4 loads issued since] ->
// vmcnt(4)@ph2. ph1(t+1) needs A/B-k0(t+1) [staged t ph1/2; 4 since] ->
// vmcnt(4)@ph4. Last tile: vmcnt(0)@ph2, skip ph4 wait.
// STORE: 0 = f32 Cf, 1 = split bf16 (Ch,Cl), 2 = bf16 (Ch).
template <int NSEG, int STORE>
__global__ __launch_bounds__(512, 2) void gemm8(
    const u16* __restrict__ A0, const u16* __restrict__ A1,
    const u16* __restrict__ A2, const u16* __restrict__ B0,
    const u16* __restrict__ B1, const u16* __restrict__ B2,
    float* __restrict__ Cf, u16* __restrict__ Ch, u16* __restrict__ Cl,
    int Kseg, int lda, int ldb, int ldc,
    long long sA, long long sB, long long sC) {
  __shared__ u16 lds[2 * 32768];  // 2 x (A 16K + B 16K) u16 = 128 KB

  const int tid = threadIdx.x;
  const int ln = tid & 63;
  const int wid = tid >> 6;
  const int wm = wid >> 2;  // 0..1
  const int wn = wid & 3;   // 0..3
  const int m0 = blockIdx.y * 256;
  const int n0 = blockIdx.x * 256;
  const int z = blockIdx.z;
  const long long za = (long long)z * sA;
  const long long zb = (long long)z * sB;

  const int NT = NSEG * (Kseg >> 6);

  f32x4 acc[8][4];
  const f32x4 zero = {0.f, 0.f, 0.f, 0.f};
#pragma unroll
  for (int i = 0; i < 8; i++)
#pragma unroll
    for (int j = 0; j < 4; j++) acc[i][j] = zero;

  auto baseA = [&](int t) -> const u16* {
    int kk = t << 6;
    const u16* p = A0;
    if (NSEG >= 2 && kk >= Kseg) { kk -= Kseg; p = A1; }
    if (NSEG >= 3 && kk >= Kseg) { kk -= Kseg; p = A2; }
    return p + za + (size_t)m0 * lda + kk;
  };
  auto baseB = [&](int t) -> const u16* {
    int kk = t << 6;
    const u16* p = B0;
    if (NSEG >= 2 && kk >= Kseg) { kk -= Kseg; p = B1; }
    if (NSEG >= 3 && kk >= Kseg) { kk -= Kseg; p = B2; }
    return p + zb + (size_t)n0 * ldb + kk;
  };
  // which: 0=A-k0, 1=B-k0, 2=A-k1, 3=B-k1; dest buffer = (t&1)
  auto stage_half = [&](int t, int which) {
    u16* dst = lds + (t & 1) * 32768 + (which & 1) * 16384 + (which >> 1) * 8192;
    const u16* gb = (which & 1) ? baseB(t) : baseA(t);
    const int ld = (which & 1) ? ldb : lda;
    const int kh = (which >> 1) * 32;
#pragma unroll
    for (int l = 0; l < 2; ++l) {
      const int c = tid + l * 512;
      const int row = ((c >> 6) << 4) + (c & 15);
      const int kk = ((c >> 4) & 3) * 8;
      gload_lds16(gb + (size_t)row * ld + kh + kk, dst + c * 8);
    }
  };

  // prologue: all 4 halves of tile 0; one-time full drain
  stage_half(0, 0); stage_half(0, 1); stage_half(0, 2); stage_half(0, 3);
  wait_vmcnt<0>();
  __builtin_amdgcn_s_barrier();
  __builtin_amdgcn_sched_barrier(0);

  for (int t = 0; t < NT; ++t) {
    const u16* buf = lds + (t & 1) * 32768;
    const u16* Asub0 = buf;
    const u16* Asub1 = buf + 8192;
    const u16* Bsub0 = buf + 16384;
    const u16* Bsub1 = buf + 24576;
    const int fo = ln * 8;
    const bool more = (t + 1 < NT);
    bf16x8 b[4], a[4];

    // ---- phase 1: (k0, m-half 0) ----
#pragma unroll
    for (int j = 0; j < 4; ++j)
      b[j] = *(const bf16x8*)(Bsub0 + (wn * 4 + j) * 512 + fo);
#pragma unroll
    for (int i = 0; i < 4; ++i)
      a[i] = *(const bf16x8*)(Asub0 + (wm * 8 + i) * 512 + fo);
    if (more) stage_half(t + 1, 0);
    __builtin_amdgcn_s_barrier();
    asm volatile("s_waitcnt lgkmcnt(0)" ::: "memory");
    __builtin_amdgcn_sched_barrier(0);
    __builtin_amdgcn_s_setprio(1);
#pragma unroll
    for (int mi = 0; mi < 4; ++mi)
#pragma unroll
      for (int ni = 0; ni < 4; ++ni)
        acc[mi][ni] = __builtin_amdgcn_mfma_f32_16x16x32_bf16(
            a[mi], b[ni], acc[mi][ni], 0, 0, 0);
    __builtin_amdgcn_s_setprio(0);
    __builtin_amdgcn_sched_barrier(0);
    __builtin_amdgcn_s_barrier();

    // ---- phase 2: (k0, m-half 1) ----
#pragma unroll
    for (int i = 0; i < 4; ++i)
      a[i] = *(const bf16x8*)(Asub0 + (wm * 8 + 4 + i) * 512 + fo);
    if (more) stage_half(t + 1, 1);
    __builtin_amdgcn_s_barrier();
    asm volatile("s_waitcnt lgkmcnt(0)" ::: "memory");
    __builtin_amdgcn_sched_barrier(0);
    __builtin_amdgcn_s_setprio(1);
#pragma unroll
    for (int mi = 0; mi < 4; ++mi)
#pragma unroll
      for (int ni = 0; ni < 4; ++ni)
        acc[4 + mi][ni] = __builtin_amdgcn_mfma_f32_16x16x32_bf16(
            a[mi], b[ni], acc[4 + mi][ni], 0, 0, 0);
    __builtin_amdgcn_s_setprio(0);
    __builtin_amdgcn_sched_barrier(0);
    if (more) wait_vmcnt<4>(); else wait_vmcnt<0>();  // A/B-k1(t) landed
    __builtin_amdgcn_s_barrier();

    // ---- phase 3: (k1, m-half 0) ----
#pragma unroll
    for (int j = 0; j < 4; ++j)
      b[j] = *(const bf16x8*)(Bsub1 + (wn * 4 + j) * 512 + fo);
#pragma unroll
    for (int i = 0; i < 4; ++i)
      a[i] = *(const bf16x8*)(Asub1 + (wm * 8 + i) * 512 + fo);
    if (more) stage_half(t + 1, 2);
    __builtin_amdgcn_s_barrier();
    asm volatile("s_waitcnt lgkmcnt(0)" ::: "memory");
    __builtin_amdgcn_sched_barrier(0);
    __builtin_amdgcn_s_setprio(1);
#pragma unroll
    for (int mi = 0; mi < 4; ++mi)
#pragma unroll
      for (int ni = 0; ni < 4; ++ni)
        acc[mi][ni] = __builtin_amdgcn_mfma_f32_16x16x32_bf16(
            a[mi], b[ni], acc[mi][ni], 0, 0, 0);
    __builtin_amdgcn_s_setprio(0);
    __builtin_amdgcn_sched_barrier(0);
    __builtin_amdgcn_s_barrier();

    // ---- phase 4: (k1, m-half 1) ----
#pragma unroll
    for (int i = 0; i < 4; ++i)
      a[i] = *(const bf16x8*)(Asub1 + (wm * 8 + 4 + i) * 512 + fo);
    if (more) stage_half(t + 1, 3);
    __builtin_amdgcn_s_barrier();
    asm volatile("s_waitcnt lgkmcnt(0)" ::: "memory");
    __builtin_amdgcn_sched_barrier(0);
    __builtin_amdgcn_s_setprio(1);
#pragma unroll
    for (int mi = 0; mi < 4; ++mi)
#pragma unroll
      for (int ni = 0; ni < 4; ++ni)
        acc[4 + mi][ni] = __builtin_amdgcn_mfma_f32_16x16x32_bf16(
            a[mi], b[ni], acc[4 + mi][ni], 0, 0, 0);
    __builtin_amdgcn_s_setprio(0);
    __builtin_amdgcn_sched_barrier(0);
    if (more) {
      wait_vmcnt<4>();  // A/B-k0(t+1) landed
      __builtin_amdgcn_s_barrier();
    }
  }

  // epilogue: C/D layout col=lane&15, row=(lane>>4)*4+reg (validated r2-r7)
  const int orow = (ln >> 4) * 4;
  const int ocol = ln & 15;
#pragma unroll
  for (int mi = 0; mi < 8; ++mi)
#pragma unroll
    for (int ni = 0; ni < 4; ++ni) {
      const int rbase = m0 + wm * 128 + mi * 16 + orow;
      const int cc = n0 + wn * 64 + ni * 16 + ocol;
#pragma unroll
      for (int i = 0; i < 4; ++i) {
        const float v = acc[mi][ni][i];
        const long long off =
            (long long)(rbase + i) * ldc + cc + (long long)z * sC;
        if (STORE == 0) {
          Cf[off] = v;
        } else if (STORE == 1) {
          const u16 h = f2bf(v);
          Ch[off] = h;
          Cl[off] = f2bf(v - bf2f(h));
        } else {
          Ch[off] = f2bf(v);
        }
      }
    }
}

// row softmax core: 2048 f32 -> 8 bf16 x4 stored to q (stride 2048 u16)
__device__ __forceinline__ void softmax_row(const float* p, u16* q) {
  const int t = threadIdx.x;
  const int wv = t >> 6, lnn = t & 63;

  float4 x0 = *(const float4*)(p + t * 4);
  float4 x1 = *(const float4*)(p + 1024 + t * 4);

  float m = fmaxf(fmaxf(fmaxf(x0.x, x0.y), fmaxf(x0.z, x0.w)),
                  fmaxf(fmaxf(x1.x, x1.y), fmaxf(x1.z, x1.w)));
#pragma unroll
  for (int off = 32; off; off >>= 1) m = fmaxf(m, __shfl_xor(m, off));
  __shared__ float redm[4];
  __shared__ float reds[4];
  if (lnn == 0) redm[wv] = m;
  __syncthreads();
  m = fmaxf(fmaxf(redm[0], redm[1]), fmaxf(redm[2], redm[3]));

  float e[8];
  e[0] = __expf(x0.x - m); e[1] = __expf(x0.y - m);
  e[2] = __expf(x0.z - m); e[3] = __expf(x0.w - m);
  e[4] = __expf(x1.x - m); e[5] = __expf(x1.y - m);
  e[6] = __expf(x1.z - m); e[7] = __expf(x1.w - m);
  float s = e[0] + e[1] + e[2] + e[3] + e[4] + e[5] + e[6] + e[7];
#pragma unroll
  for (int off = 32; off; off >>= 1) s += __shfl_xor(s, off);
  if (lnn == 0) reds[wv] = s;
  __syncthreads();
  const float inv = 1.f / (reds[0] + reds[1] + reds[2] + reds[3]);

  ushort4 o0, o1;
  o0.x = f2bf(e[0] * inv); o0.y = f2bf(e[1] * inv);
  o0.z = f2bf(e[2] * inv); o0.w = f2bf(e[3] * inv);
  o1.x = f2bf(e[4] * inv); o1.y = f2bf(e[5] * inv);
  o1.z = f2bf(e[6] * inv); o1.w = f2bf(e[7] * inv);
  *(ushort4*)(q + t * 4) = o0;
  *(ushort4*)(q + 1024 + t * 4) = o1;
}

// in place: P overwrites L rows (P row stride stays 4096 u16)
__global__ __launch_bounds__(256) void softmax_inplace(float* __restrict__ L) {
  float* p = L + (size_t)blockIdx.x * 2048;
  softmax_row(p, (u16*)p);
}

// to separate bf16 buffer (row stride 2048 u16)
__global__ __launch_bounds__(256) void softmax_out(
    const float* __restrict__ L, u16* __restrict__ P) {
  softmax_row(L + (size_t)blockIdx.x * 2048, P + (size_t)blockIdx.x * 2048);
}

extern "C" void kernel_launch(void* const* d_in, const int* in_sizes, int n_in,
                              void* d_out, int out_size, void* d_ws, size_t ws_size,
                              hipStream_t stream) {
  constexpr int Bn = 4, S = 2048, D = 1024;
  constexpr long long TOK = (long long)Bn * S;  // 8192
  constexpr long long DD = (long long)D * D;
  const float* X = (const float*)d_in[0];
  const float* Wq = (const float*)d_in[1];
  const float* Wk = (const float*)d_in[2];
  const float* Wv = (const float*)d_in[3];
  float* out = (float*)d_out;
  const dim3 blk(256);
  const dim3 gblk(512);

  char* w = (char*)d_ws;
  auto au16 = [&](long long n) { u16* p = (u16*)w; w += n * 2; return p; };

  // exact byte budgets
  const bool full = ws_size >= (size_t)195035136ULL;  // + Lf G=4 (64MB)
  const bool midp = ws_size >= (size_t)161480704ULL;  // + P_all bf16 (32MB)
  const bool mid  = ws_size >= (size_t)127926272ULL;  // Lf aliases Xh/Xl

  if (full || midp || mid) {
    u16* Xh = au16(TOK * D);
    u16* Xl = au16(TOK * D);
    u16* Wch = au16(2 * DD);  // [Wq;Wk] hi
    u16* Wcl = au16(2 * DD);
    u16* Wvh = au16(DD);
    u16* QKh = au16(TOK * 2 * D);  // cols 0..1023 = Q, 1024..2047 = K
    u16* QKl = au16(TOK * 2 * D);
    u16* VT = au16((long long)D * TOK);  // [1024][8192], col = b*2048+s

    split_f32_kernel<true><<<2048, blk, 0, stream>>>(X, Xh, Xl, TOK * D);
    split_f32_kernel<true><<<512, blk, 0, stream>>>(Wq, Wch, Wcl, DD);
    split_f32_kernel<true><<<512, blk, 0, stream>>>(Wk, Wch + DD, Wcl + DD, DD);
    split_f32_kernel<false><<<512, blk, 0, stream>>>(Wv, Wvh, nullptr, DD);

    // fused Q|K projection: M=8192, N=2048 -> (8,32) = 256 blocks
    gemm8<3, 1><<<dim3(8, 32, 1), gblk, 0, stream>>>(
        Xh, Xh, Xl, Wch, Wcl, Wch, nullptr, QKh, QKl,
        D, D, D, 2 * D, 0, 0, 0);
    // VT[e,tok] = Wvh . Xh^T : M=1024, N=8192 -> (32,4) = 128 blocks
    gemm8<1, 2><<<dim3(32, 4, 1), gblk, 0, stream>>>(
        Wvh, nullptr, nullptr, Xh, nullptr, nullptr, nullptr, VT, nullptr,
        D, D, D, (int)TOK, 0, 0, 0);

    if (full) {
      float* Lf = (float*)w;  // 4*S*S f32
      gemm8<3, 0><<<dim3(8, 8, 4), gblk, 0, stream>>>(
          QKh, QKh, QKl, QKh + D, QKl + D, QKh + D,
          Lf, nullptr, nullptr, D, 2 * D, 2 * D, S,
          (long long)S * 2 * D, (long long)S * 2 * D, (long long)S * S);
      softmax_inplace<<<dim3(4 * S), blk, 0, stream>>>(Lf);
      gemm8<1, 0><<<dim3(4, 8, 4), gblk, 0, stream>>>(
          (const u16*)Lf, nullptr, nullptr, VT, nullptr, nullptr,
          out, nullptr, nullptr, S, 2 * S, (int)TOK, D,
          (long long)S * S * 2, (long long)S, (long long)S * D);
    } else if (midp) {
      u16* Pall = au16((long long)Bn * S * S);  // bf16 P, all batches
      float* Lf = (float*)d_ws;  // aliases [Xh|Xl] (dead), 2*S*S*4 bytes
      for (int g = 0; g < 2; ++g) {
        const long long ro = (long long)g * 2 * S * 2 * D;
        gemm8<3, 0><<<dim3(8, 8, 2), gblk, 0, stream>>>(
            QKh + ro, QKh + ro, QKl + ro,
            QKh + ro + D, QKl + ro + D, QKh + ro + D,
            Lf, nullptr, nullptr, D, 2 * D, 2 * D, S,
            (long long)S * 2 * D, (long long)S * 2 * D, (long long)S * S);
        softmax_out<<<dim3(2 * S), blk, 0, stream>>>(
            Lf, Pall + (long long)g * 2 * S * S);
      }
      gemm8<1, 0><<<dim3(4, 8, 4), gblk, 0, stream>>>(
          Pall, nullptr, nullptr, VT, nullptr, nullptr,
          out, nullptr, nullptr, S, S, (int)TOK, D,
          (long long)S * S, (long long)S, (long long)S * D);
    } else {
      float* Lf = (float*)d_ws;  // aliases [Xh|Xl]
      for (int g = 0; g < 2; ++g) {
        const long long ro = (long long)g * 2 * S * 2 * D;
        gemm8<3, 0><<<dim3(8, 8, 2), gblk, 0, stream>>>(
            QKh + ro, QKh + ro, QKl + ro,
            QKh + ro + D, QKl + ro + D, QKh + ro + D,
            Lf, nullptr, nullptr, D, 2 * D, 2 * D, S,
            (long long)S * 2 * D, (long long)S * 2 * D, (long long)S * S);
        softmax_inplace<<<dim3(2 * S), blk, 0, stream>>>(Lf);
        gemm8<1, 0><<<dim3(4, 8, 2), gblk, 0, stream>>>(
            (const u16*)Lf, nullptr, nullptr, VT + (long long)g * 2 * S,
            nullptr, nullptr, out + (long long)g * 2 * S * D, nullptr,
            nullptr, S, 2 * S, (int)TOK, D,
            (long long)S * S * 2, (long long)S, (long long)S * D);
      }
    }
  } else {
    // Low tier (~82 MB): per-batch
    u16* Xh = au16(TOK * D);
    u16* Xl = au16(TOK * D);
    u16* Wch = au16(2 * DD);
    u16* Wcl = au16(2 * DD);
    u16* Wvh = au16(DD);
    u16* QKhb = au16((long long)S * 2 * D);
    u16* QKlb = au16((long long)S * 2 * D);
    u16* VTb = au16((long long)D * S);
    float* Lb = (float*)w;

    split_f32_kernel<true><<<2048, blk, 0, stream>>>(X, Xh, Xl, TOK * D);
    split_f32_kernel<true><<<512, blk, 0, stream>>>(Wq, Wch, Wcl, DD);
    split_f32_kernel<true><<<512, blk, 0, stream>>>(Wk, Wch + DD, Wcl + DD, DD);
    split_f32_kernel<false><<<512, blk, 0, stream>>>(Wv, Wvh, nullptr, DD);

    for (int b = 0; b < Bn; ++b) {
      const long long xo = (long long)b * S * D;
      gemm8<3, 1><<<dim3(8, 8, 1), gblk, 0, stream>>>(
          Xh + xo, Xh + xo, Xl + xo, Wch, Wcl, Wch, nullptr, QKhb, QKlb,
          D, D, D, 2 * D, 0, 0, 0);
      gemm8<1, 2><<<dim3(8, 4, 1), gblk, 0, stream>>>(
          Wvh, nullptr, nullptr, Xh + xo, nullptr, nullptr, nullptr, VTb,
          nullptr, D, D, D, S, 0, 0, 0);
      gemm8<3, 0><<<dim3(8, 8, 1), gblk, 0, stream>>>(
          QKhb, QKhb, QKlb, QKhb + D, QKlb + D, QKhb + D,
          Lb, nullptr, nullptr, D, 2 * D, 2 * D, S, 0, 0, 0);
      softmax_inplace<<<dim3(S), blk, 0, stream>>>(Lb);
      gemm8<1, 0><<<dim3(4, 8, 1), gblk, 0, stream>>>(
          (const u16*)Lb, nullptr, nullptr, VTb, nullptr, nullptr,
          out + xo, nullptr, nullptr, S, 2 * S, S, D, 0, 0, 0);
    }
  }
}

// Round 9
// 478.632 us; speedup vs baseline: 2.0744x; 1.1699x over previous
//
#include <hip/hip_runtime.h>
#include <math.h>

// SelfAttention B=4,S=2048,D=1024 fp32. Round 9: revert to r4's proven GEMM
// ledger (256^2/BK=32/3 LDS slots/stage lead 2/one barrier + counted vmcnt
// per tile), add M_REP=4 (BM=128) variant for full grids, and make QKT a
// single z=4 launch in all tiers (split-bf16 L when f32 L doesn't fit).
// Numerics: split-bf16 concat-K (hh+hl+lh) logit chain, validated r2-r8.

typedef unsigned short u16;
typedef __attribute__((ext_vector_type(8))) short bf16x8;
typedef __attribute__((ext_vector_type(4))) float f32x4;

__device__ __forceinline__ u16 f2bf(float x) {
  unsigned u = __float_as_uint(x);
  unsigned r = (u + 0x7fffu + ((u >> 16) & 1u)) >> 16;
  return (u16)r;
}
__device__ __forceinline__ float bf2f(u16 h) {
  return __uint_as_float((unsigned)h << 16);
}

__device__ __forceinline__ void gload_lds16(const u16* g, u16* l) {
  __builtin_amdgcn_global_load_lds(
      (const __attribute__((address_space(1))) unsigned int*)(g),
      (__attribute__((address_space(3))) unsigned int*)(l), 16, 0, 0);
}

template <int N>
__device__ __forceinline__ void wait_vmcnt() {
  if constexpr (N == 0) asm volatile("s_waitcnt vmcnt(0)" ::: "memory");
  else if constexpr (N == 3) asm volatile("s_waitcnt vmcnt(3)" ::: "memory");
  else if constexpr (N == 4) asm volatile("s_waitcnt vmcnt(4)" ::: "memory");
}

// fp32 -> hi bf16 (+ optional lo bf16), grid-stride, vectorized
template <bool LO>
__global__ __launch_bounds__(256) void split_f32_kernel(
    const float* __restrict__ in, u16* __restrict__ hi, u16* __restrict__ lo,
    long long n) {
  long long i = ((long long)blockIdx.x * 256 + threadIdx.x) * 4;
  const long long step = (long long)gridDim.x * 256 * 4;
  for (; i < n; i += step) {
    float4 x = *(const float4*)(in + i);
    float xs[4] = {x.x, x.y, x.z, x.w};
    u16 hv[4], lv[4];
#pragma unroll
    for (int j = 0; j < 4; j++) {
      hv[j] = f2bf(xs[j]);
      if (LO) lv[j] = f2bf(xs[j] - bf2f(hv[j]));
    }
    ushort4 h;
    h.x = hv[0]; h.y = hv[1]; h.z = hv[2]; h.w = hv[3];
    *(ushort4*)(hi + i) = h;
    if (LO) {
      ushort4 l;
      l.x = lv[0]; l.y = lv[1]; l.z = lv[2]; l.w = lv[3];
      *(ushort4*)(lo + i) = l;
    }
  }
}

// NT GEMM over NSEG K-segments. BM=32*M_REP (128 or 256), BN=256, BK=32.
// 512 thr = 8 waves (2M x 4N); per-wave (M_REP*16) x 64 output.
// LDS: 3 slots x (A BM*32 + B 256*32) u16; subtile layout per tile:
//   elem(row,k) at u16 off (row>>4)*512 + ((k>>3)&3)*128 + (row&15)*8 + (k&7)
//   stage chunk c -> row=((c>>6)<<4)+(c&15), k=((c>>4)&3)*8 (linear dest)
//   frag read rowblock rb: rb*512 + lane*8 -> conflict-free ds_read_b128.
// r4-proven ledger: compute tile t from slot[t%3]; stage tile t+2 into
// slot[(t+2)%3] (freed by the barrier at end of t-1); ONE barrier per tile
// preceded by counted vmcnt(L) (L = loads/thread/tile; proves tile t+1
// landed, only the t+2 loads may still fly). Never vmcnt(0) mid-loop.
// STORE: 0 = f32 Cf, 1 = split bf16 (Ch,Cl), 2 = bf16 (Ch).
template <int NSEG, int STORE, int M_REP>
__global__ __launch_bounds__(512, 2) void gemmc(
    const u16* __restrict__ A0, const u16* __restrict__ A1,
    const u16* __restrict__ A2, const u16* __restrict__ B0,
    const u16* __restrict__ B1, const u16* __restrict__ B2,
    float* __restrict__ Cf, u16* __restrict__ Ch, u16* __restrict__ Cl,
    int Kseg, int lda, int ldb, int ldc,
    long long sA, long long sB, long long sC) {
  constexpr int BM = 32 * M_REP;
  constexpr int ASZ = BM * 32;   // u16
  constexpr int BSZ = 8192;      // 256x32 u16
  constexpr int SLOT = ASZ + BSZ;
  constexpr int LA = M_REP / 4;  // A gloads / thread / tile (1 or 2)
  constexpr int L = LA + 2;      // + 2 B gloads
  __shared__ u16 lds[3 * SLOT];

  const int tid = threadIdx.x;
  const int ln = tid & 63;
  const int wid = tid >> 6;
  const int wm = wid >> 2;  // 0..1
  const int wn = wid & 3;   // 0..3
  const int m0 = blockIdx.y * BM;
  const int n0 = blockIdx.x * 256;
  const int z = blockIdx.z;
  const long long za = (long long)z * sA;
  const long long zb = (long long)z * sB;

  const int NT = NSEG * (Kseg >> 5);

  f32x4 acc[M_REP][4];
  const f32x4 zero = {0.f, 0.f, 0.f, 0.f};
#pragma unroll
  for (int i = 0; i < M_REP; i++)
#pragma unroll
    for (int j = 0; j < 4; j++) acc[i][j] = zero;

  auto baseA = [&](int t) -> const u16* {
    int kk = t << 5;
    const u16* p = A0;
    if (NSEG >= 2 && kk >= Kseg) { kk -= Kseg; p = A1; }
    if (NSEG >= 3 && kk >= Kseg) { kk -= Kseg; p = A2; }
    return p + za + (size_t)m0 * lda + kk;
  };
  auto baseB = [&](int t) -> const u16* {
    int kk = t << 5;
    const u16* p = B0;
    if (NSEG >= 2 && kk >= Kseg) { kk -= Kseg; p = B1; }
    if (NSEG >= 3 && kk >= Kseg) { kk -= Kseg; p = B2; }
    return p + zb + (size_t)n0 * ldb + kk;
  };
  auto stage = [&](int t) {
    u16* slot = lds + (t % 3) * SLOT;
    const u16* Ab = baseA(t);
    const u16* Bb = baseB(t);
#pragma unroll
    for (int l = 0; l < LA; ++l) {
      const int c = tid + l * 512;
      const int row = ((c >> 6) << 4) + (c & 15);
      const int kk = ((c >> 4) & 3) * 8;
      gload_lds16(Ab + (size_t)row * lda + kk, slot + c * 8);
    }
#pragma unroll
    for (int l = 0; l < 2; ++l) {
      const int c = tid + l * 512;
      const int row = ((c >> 6) << 4) + (c & 15);
      const int kk = ((c >> 4) & 3) * 8;
      gload_lds16(Bb + (size_t)row * ldb + kk, slot + ASZ + c * 8);
    }
  };

  // prologue: tiles 0,1 in flight; wait tile 0 (t1's L loads may fly)
  stage(0);
  stage(1);
  wait_vmcnt<L>();
  __builtin_amdgcn_s_barrier();
  __builtin_amdgcn_sched_barrier(0);

  for (int t = 0; t < NT; ++t) {
    if (t + 2 < NT) stage(t + 2);
    const u16* Abuf = lds + (t % 3) * SLOT;
    const u16* Bbuf = Abuf + ASZ;
    const int fo = ln * 8;
    bf16x8 a[M_REP], b[4];
#pragma unroll
    for (int j = 0; j < 4; ++j)
      b[j] = *(const bf16x8*)(Bbuf + (wn * 4 + j) * 512 + fo);
#pragma unroll
    for (int i = 0; i < M_REP; ++i)
      a[i] = *(const bf16x8*)(Abuf + (wm * M_REP + i) * 512 + fo);
    __builtin_amdgcn_s_setprio(1);
#pragma unroll
    for (int i = 0; i < M_REP; ++i)
#pragma unroll
      for (int j = 0; j < 4; ++j)
        acc[i][j] = __builtin_amdgcn_mfma_f32_16x16x32_bf16(
            a[i], b[j], acc[i][j], 0, 0, 0);
    __builtin_amdgcn_s_setprio(0);
    if (t + 1 < NT) {
      if (t + 2 < NT) wait_vmcnt<L>();  // tile t+1 landed; t+2 may fly
      else            wait_vmcnt<0>();  // drain tail
      __builtin_amdgcn_s_barrier();
      __builtin_amdgcn_sched_barrier(0);
    }
  }

  // epilogue: C/D layout col=lane&15, row=(lane>>4)*4+reg (validated r2-r8)
  const int orow = (ln >> 4) * 4;
  const int ocol = ln & 15;
#pragma unroll
  for (int mi = 0; mi < M_REP; ++mi)
#pragma unroll
    for (int ni = 0; ni < 4; ++ni) {
      const int rbase = m0 + wm * (M_REP * 16) + mi * 16 + orow;
      const int cc = n0 + wn * 64 + ni * 16 + ocol;
#pragma unroll
      for (int i = 0; i < 4; ++i) {
        const float v = acc[mi][ni][i];
        const long long off =
            (long long)(rbase + i) * ldc + cc + (long long)z * sC;
        if (STORE == 0) {
          Cf[off] = v;
        } else if (STORE == 1) {
          const u16 h = f2bf(v);
          Ch[off] = h;
          Cl[off] = f2bf(v - bf2f(h));
        } else {
          Ch[off] = f2bf(v);
        }
      }
    }
}

// ---- softmax kernels (row = 2048) ----
__device__ __forceinline__ float blk_max(float v, float* red) {
  const int wv = threadIdx.x >> 6, lnn = threadIdx.x & 63;
#pragma unroll
  for (int off = 32; off; off >>= 1) v = fmaxf(v, __shfl_xor(v, off));
  if (lnn == 0) red[wv] = v;
  __syncthreads();
  return fmaxf(fmaxf(red[0], red[1]), fmaxf(red[2], red[3]));
}
__device__ __forceinline__ float blk_sum(float v, float* red) {
  const int wv = threadIdx.x >> 6, lnn = threadIdx.x & 63;
#pragma unroll
  for (int off = 32; off; off >>= 1) v += __shfl_xor(v, off);
  if (lnn == 0) red[wv] = v;
  __syncthreads();
  return red[0] + red[1] + red[2] + red[3];
}

// f32 L row -> bf16 P in place (row stride stays 4096 u16)
__global__ __launch_bounds__(256) void softmax_inplace(float* __restrict__ L) {
  float* p = L + (size_t)blockIdx.x * 2048;
  const int t = threadIdx.x;
  __shared__ float redm[4];
  __shared__ float reds[4];

  float4 x0 = *(const float4*)(p + t * 4);
  float4 x1 = *(const float4*)(p + 1024 + t * 4);
  float m = fmaxf(fmaxf(fmaxf(x0.x, x0.y), fmaxf(x0.z, x0.w)),
                  fmaxf(fmaxf(x1.x, x1.y), fmaxf(x1.z, x1.w)));
  m = blk_max(m, redm);
  float e[8];
  e[0] = __expf(x0.x - m); e[1] = __expf(x0.y - m);
  e[2] = __expf(x0.z - m); e[3] = __expf(x0.w - m);
  e[4] = __expf(x1.x - m); e[5] = __expf(x1.y - m);
  e[6] = __expf(x1.z - m); e[7] = __expf(x1.w - m);
  float s = e[0] + e[1] + e[2] + e[3] + e[4] + e[5] + e[6] + e[7];
  s = blk_sum(s, reds);
  const float inv = 1.f / s;
  u16* q = (u16*)p;
  ushort4 o0, o1;
  o0.x = f2bf(e[0] * inv); o0.y = f2bf(e[1] * inv);
  o0.z = f2bf(e[2] * inv); o0.w = f2bf(e[3] * inv);
  o1.x = f2bf(e[4] * inv); o1.y = f2bf(e[5] * inv);
  o1.z = f2bf(e[6] * inv); o1.w = f2bf(e[7] * inv);
  *(ushort4*)(q + t * 4) = o0;
  *(ushort4*)(q + 1024 + t * 4) = o1;
}

// split-bf16 L (Lh+Ll, row stride 2048 u16 each) -> bf16 P over Lh row
__global__ __launch_bounds__(256) void softmax_split(
    u16* __restrict__ Lh, const u16* __restrict__ Ll) {
  u16* ph = Lh + (size_t)blockIdx.x * 2048;
  const u16* pl = Ll + (size_t)blockIdx.x * 2048;
  const int t = threadIdx.x;
  __shared__ float redm[4];
  __shared__ float reds[4];

  ushort4 h0 = *(const ushort4*)(ph + t * 4);
  ushort4 h1 = *(const ushort4*)(ph + 1024 + t * 4);
  ushort4 l0 = *(const ushort4*)(pl + t * 4);
  ushort4 l1 = *(const ushort4*)(pl + 1024 + t * 4);
  float x[8];
  x[0] = bf2f(h0.x) + bf2f(l0.x); x[1] = bf2f(h0.y) + bf2f(l0.y);
  x[2] = bf2f(h0.z) + bf2f(l0.z); x[3] = bf2f(h0.w) + bf2f(l0.w);
  x[4] = bf2f(h1.x) + bf2f(l1.x); x[5] = bf2f(h1.y) + bf2f(l1.y);
  x[6] = bf2f(h1.z) + bf2f(l1.z); x[7] = bf2f(h1.w) + bf2f(l1.w);
  float m = fmaxf(fmaxf(fmaxf(x[0], x[1]), fmaxf(x[2], x[3])),
                  fmaxf(fmaxf(x[4], x[5]), fmaxf(x[6], x[7])));
  m = blk_max(m, redm);
  float e[8];
#pragma unroll
  for (int j = 0; j < 8; ++j) e[j] = __expf(x[j] - m);
  float s = e[0] + e[1] + e[2] + e[3] + e[4] + e[5] + e[6] + e[7];
  s = blk_sum(s, reds);
  const float inv = 1.f / s;
  ushort4 o0, o1;
  o0.x = f2bf(e[0] * inv); o0.y = f2bf(e[1] * inv);
  o0.z = f2bf(e[2] * inv); o0.w = f2bf(e[3] * inv);
  o1.x = f2bf(e[4] * inv); o1.y = f2bf(e[5] * inv);
  o1.z = f2bf(e[6] * inv); o1.w = f2bf(e[7] * inv);
  *(ushort4*)(ph + t * 4) = o0;
  *(ushort4*)(ph + 1024 + t * 4) = o1;
}

extern "C" void kernel_launch(void* const* d_in, const int* in_sizes, int n_in,
                              void* d_out, int out_size, void* d_ws, size_t ws_size,
                              hipStream_t stream) {
  constexpr int Bn = 4, S = 2048, D = 1024;
  constexpr long long TOK = (long long)Bn * S;  // 8192
  constexpr long long DD = (long long)D * D;
  const float* X = (const float*)d_in[0];
  const float* Wq = (const float*)d_in[1];
  const float* Wk = (const float*)d_in[2];
  const float* Wv = (const float*)d_in[3];
  float* out = (float*)d_out;
  const dim3 blk(256);
  const dim3 gblk(512);

  char* w = (char*)d_ws;
  auto au16 = [&](long long n) { u16* p = (u16*)w; w += n * 2; return p; };

  // exact byte budgets (base = 127,926,272)
  const bool tA = ws_size >= (size_t)195035136ULL;  // + f32 L (67.1 MB tail)
  const bool tB = ws_size >= (size_t)161480704ULL;  // + Ll bf16 (33.55 tail)
  const bool tC = ws_size >= (size_t)140000000ULL;  // L aliases Xh/Xl, G=2

  if (tA || tB || tC) {
    u16* Xh = au16(TOK * D);
    u16* Xl = au16(TOK * D);
    u16* Wch = au16(2 * DD);  // [Wq;Wk] hi
    u16* Wcl = au16(2 * DD);
    u16* Wvh = au16(DD);
    u16* QKh = au16(TOK * 2 * D);  // cols 0..1023 = Q, 1024..2047 = K
    u16* QKl = au16(TOK * 2 * D);
    u16* VT = au16((long long)D * TOK);  // [1024][8192], col = b*2048+s

    split_f32_kernel<true><<<2048, blk, 0, stream>>>(X, Xh, Xl, TOK * D);
    split_f32_kernel<true><<<512, blk, 0, stream>>>(Wq, Wch, Wcl, DD);
    split_f32_kernel<true><<<512, blk, 0, stream>>>(Wk, Wch + DD, Wcl + DD, DD);
    split_f32_kernel<false><<<512, blk, 0, stream>>>(Wv, Wvh, nullptr, DD);

    // fused Q|K projection: M=8192, N=2048 -> (8,32) = 256 blocks
    gemmc<3, 1, 8><<<dim3(8, 32, 1), gblk, 0, stream>>>(
        Xh, Xh, Xl, Wch, Wcl, Wch, nullptr, QKh, QKl,
        D, D, D, 2 * D, 0, 0, 0);
    // VT[e,tok] = Wvh . Xh^T : M=1024, N=8192, BM=128 -> (32,8) = 256 blocks
    gemmc<1, 2, 4><<<dim3(32, 8, 1), gblk, 0, stream>>>(
        Wvh, nullptr, nullptr, Xh, nullptr, nullptr, nullptr, VT, nullptr,
        D, D, D, (int)TOK, 0, 0, 0);
    // X/W buffers are dead from here on (44.03 MB at d_ws offset 0).

    if (tA) {
      float* Lf = (float*)w;  // 4*S*S f32 tail
      gemmc<3, 0, 8><<<dim3(8, 8, 4), gblk, 0, stream>>>(
          QKh, QKh, QKl, QKh + D, QKl + D, QKh + D,
          Lf, nullptr, nullptr, D, 2 * D, 2 * D, S,
          (long long)S * 2 * D, (long long)S * 2 * D, (long long)S * S);
      softmax_inplace<<<dim3(4 * S), blk, 0, stream>>>(Lf);
      // O = P . VT^T : BM=128 -> (4,16,4) = 256 blocks
      gemmc<1, 0, 4><<<dim3(4, 16, 4), gblk, 0, stream>>>(
          (const u16*)Lf, nullptr, nullptr, VT, nullptr, nullptr,
          out, nullptr, nullptr, S, 2 * S, (int)TOK, D,
          (long long)S * S * 2, (long long)S, (long long)S * D);
    } else if (tB) {
      u16* Lh = (u16*)d_ws;   // over dead X/W region (33.55 <= 44.03 MB)
      u16* Ll = au16((long long)Bn * S * S);  // 33.55 MB tail
      gemmc<3, 1, 8><<<dim3(8, 8, 4), gblk, 0, stream>>>(
          QKh, QKh, QKl, QKh + D, QKl + D, QKh + D,
          nullptr, Lh, Ll, D, 2 * D, 2 * D, S,
          (long long)S * 2 * D, (long long)S * 2 * D, (long long)S * S);
      softmax_split<<<dim3(4 * S), blk, 0, stream>>>(Lh, Ll);
      gemmc<1, 0, 4><<<dim3(4, 16, 4), gblk, 0, stream>>>(
          Lh, nullptr, nullptr, VT, nullptr, nullptr,
          out, nullptr, nullptr, S, S, (int)TOK, D,
          (long long)S * S, (long long)S, (long long)S * D);
    } else {
      float* Lf = (float*)d_ws;  // 2 batches over dead X region
      for (int g = 0; g < 2; ++g) {
        const long long ro = (long long)g * 2 * S * 2 * D;
        // BM=128 -> (8,16,2) = 256 blocks per launch
        gemmc<3, 0, 4><<<dim3(8, 16, 2), gblk, 0, stream>>>(
            QKh + ro, QKh + ro, QKl + ro,
            QKh + ro + D, QKl + ro + D, QKh + ro + D,
            Lf, nullptr, nullptr, D, 2 * D, 2 * D, S,
            (long long)S * 2 * D, (long long)S * 2 * D, (long long)S * S);
        softmax_inplace<<<dim3(2 * S), blk, 0, stream>>>(Lf);
        gemmc<1, 0, 4><<<dim3(4, 16, 2), gblk, 0, stream>>>(
            (const u16*)Lf, nullptr, nullptr, VT + (long long)g * 2 * S,
            nullptr, nullptr, out + (long long)g * 2 * S * D, nullptr,
            nullptr, S, 2 * S, (int)TOK, D,
            (long long)S * S * 2, (long long)S, (long long)S * D);
      }
    }
  } else {
    // Low tier (~82 MB): per-batch
    u16* Xh = au16(TOK * D);
    u16* Xl = au16(TOK * D);
    u16* Wch = au16(2 * DD);
    u16* Wcl = au16(2 * DD);
    u16* Wvh = au16(DD);
    u16* QKhb = au16((long long)S * 2 * D);
    u16* QKlb = au16((long long)S * 2 * D);
    u16* VTb = au16((long long)D * S);
    float* Lb = (float*)w;

    split_f32_kernel<true><<<2048, blk, 0, stream>>>(X, Xh, Xl, TOK * D);
    split_f32_kernel<true><<<512, blk, 0, stream>>>(Wq, Wch, Wcl, DD);
    split_f32_kernel<true><<<512, blk, 0, stream>>>(Wk, Wch + DD, Wcl + DD, DD);
    split_f32_kernel<false><<<512, blk, 0, stream>>>(Wv, Wvh, nullptr, DD);

    for (int b = 0; b < Bn; ++b) {
      const long long xo = (long long)b * S * D;
      gemmc<3, 1, 8><<<dim3(8, 8, 1), gblk, 0, stream>>>(
          Xh + xo, Xh + xo, Xl + xo, Wch, Wcl, Wch, nullptr, QKhb, QKlb,
          D, D, D, 2 * D, 0, 0, 0);
      gemmc<1, 2, 4><<<dim3(8, 8, 1), gblk, 0, stream>>>(
          Wvh, nullptr, nullptr, Xh + xo, nullptr, nullptr, nullptr, VTb,
          nullptr, D, D, D, S, 0, 0, 0);
      gemmc<3, 0, 4><<<dim3(8, 16, 1), gblk, 0, stream>>>(
          QKhb, QKhb, QKlb, QKhb + D, QKlb + D, QKhb + D,
          Lb, nullptr, nullptr, D, 2 * D, 2 * D, S, 0, 0, 0);
      softmax_inplace<<<dim3(S), blk, 0, stream>>>(Lb);
      gemmc<1, 0, 4><<<dim3(4, 16, 1), gblk, 0, stream>>>(
          (const u16*)Lb, nullptr, nullptr, VTb, nullptr, nullptr,
          out + xo, nullptr, nullptr, S, 2 * S, S, D, 0, 0, 0);
    }
  }
}